// Round 2
// baseline (236.383 us; speedup 1.0000x reference)
//
#include <hip/hip_runtime.h>
#include <stdint.h>

// Problem constants (fixed by reference setup_inputs): B=4096, D=512, L=80
#define B_ROWS 4096
#define DIMS   512
#define NLAB   80
#define HALF_ROWS 2048
#define HCNT   8388608u   // B*B/2 = 2^23, threefry counter split point
#define NSEG   5

typedef unsigned long long u64;

__device__ __forceinline__ uint32_t rotl32(uint32_t x, uint32_t d) {
    return (x << d) | (x >> (32u - d));
}

// JAX threefry2x32 with key = (0, 42)
__device__ __forceinline__ void tf2x32_key42(uint32_t c0, uint32_t c1,
                                             uint32_t& o0, uint32_t& o1) {
    const uint32_t ks0 = 0u;
    const uint32_t ks1 = 42u;
    const uint32_t ks2 = 0x1BD11BDAu ^ 0u ^ 42u;
    uint32_t x0 = c0 + ks0;
    uint32_t x1 = c1 + ks1;
#define TF_RND(r) { x0 += x1; x1 = rotl32(x1, (r)); x1 ^= x0; }
    TF_RND(13u) TF_RND(15u) TF_RND(26u) TF_RND(6u)
    x0 += ks1; x1 += ks2 + 1u;
    TF_RND(17u) TF_RND(29u) TF_RND(16u) TF_RND(24u)
    x0 += ks2; x1 += ks0 + 2u;
    TF_RND(13u) TF_RND(15u) TF_RND(26u) TF_RND(6u)
    x0 += ks0; x1 += ks1 + 3u;
    TF_RND(17u) TF_RND(29u) TF_RND(16u) TF_RND(24u)
    x0 += ks1; x1 += ks2 + 4u;
    TF_RND(13u) TF_RND(15u) TF_RND(26u) TF_RND(6u)
    x0 += ks2; x1 += ks0 + 5u;
#undef TF_RND
    o0 = x0; o1 = x1;
}

__device__ __forceinline__ u64 shflx64(u64 v, int m) {
    uint32_t lo = __shfl_xor((uint32_t)(v & 0xFFFFFFFFull), m, 64);
    uint32_t hi = __shfl_xor((uint32_t)(v >> 32), m, 64);
    return ((u64)hi << 32) | (u64)lo;
}

__device__ __forceinline__ u64 umax64(u64 a, u64 b) { return a > b ? a : b; }
__device__ __forceinline__ u64 umin64(u64 a, u64 b) { return a < b ? a : b; }

// keep sorted-descending top-5 (all keys globally distinct: low bits hold ~j)
__device__ __forceinline__ void top5_insert(u64* t, u64 k) {
    if (k > t[4]) {
        t[4] = k;
        u64 tmp;
        if (t[4] > t[3]) { tmp = t[3]; t[3] = t[4]; t[4] = tmp; }
        if (t[3] > t[2]) { tmp = t[2]; t[2] = t[3]; t[3] = tmp; }
        if (t[2] > t[1]) { tmp = t[1]; t[1] = t[2]; t[2] = tmp; }
        if (t[1] > t[0]) { tmp = t[0]; t[0] = t[1]; t[1] = tmp; }
    }
}

// merge two sorted-desc 5-lists, keep top-5 (register-only network)
__device__ __forceinline__ void merge_top5(u64* A, const u64* Bv) {
    u64 a0=A[0],a1=A[1],a2=A[2],a3=A[3],a4=A[4];
    u64 b0=Bv[0],b1=Bv[1],b2=Bv[2],b3=Bv[3],b4=Bv[4];
    u64 m0 = umax64(a0, b0);
    u64 m1 = umax64(umax64(a1, b1), umin64(a0, b0));
    u64 m2 = umax64(umax64(a2, b2), umax64(umin64(a0, b1), umin64(a1, b0)));
    u64 m3 = umax64(umax64(a3, b3),
                    umax64(umax64(umin64(a0, b2), umin64(a1, b1)), umin64(a2, b0)));
    u64 m4 = umax64(umax64(a4, b4),
                    umax64(umax64(umin64(a0, b3), umin64(a1, b2)),
                           umax64(umin64(a2, b1), umin64(a3, b0))));
    A[0]=m0; A[1]=m1; A[2]=m2; A[3]=m3; A[4]=m4;
}

__device__ __forceinline__ uint32_t inter3(uint4 a, uint4 b) {
    return (uint32_t)(__popc(a.x & b.x) + __popc(a.y & b.y) + __popc(a.z & b.z));
}

// ---------------- kernels ----------------

// one thread per row, int4-vectorized label loads (row = 80 ints = 20 int4)
__global__ __launch_bounds__(64) void pack_kernel(const int* __restrict__ labels,
                                                  uint4* __restrict__ packed) {
    int r = blockIdx.x * 64 + threadIdx.x;
    if (r >= B_ROWS) return;
    const int4* row = (const int4*)(labels + (size_t)r * NLAB);
    uint32_t w0 = 0, w1 = 0, w2 = 0;
#pragma unroll
    for (int q = 0; q < 8; ++q) {
        int4 v = row[q];
        w0 |= (v.x != 0 ? 1u : 0u) << (4 * q + 0);
        w0 |= (v.y != 0 ? 1u : 0u) << (4 * q + 1);
        w0 |= (v.z != 0 ? 1u : 0u) << (4 * q + 2);
        w0 |= (v.w != 0 ? 1u : 0u) << (4 * q + 3);
    }
#pragma unroll
    for (int q = 0; q < 8; ++q) {
        int4 v = row[8 + q];
        w1 |= (v.x != 0 ? 1u : 0u) << (4 * q + 0);
        w1 |= (v.y != 0 ? 1u : 0u) << (4 * q + 1);
        w1 |= (v.z != 0 ? 1u : 0u) << (4 * q + 2);
        w1 |= (v.w != 0 ? 1u : 0u) << (4 * q + 3);
    }
#pragma unroll
    for (int q = 0; q < 4; ++q) {
        int4 v = row[16 + q];
        w2 |= (v.x != 0 ? 1u : 0u) << (4 * q + 0);
        w2 |= (v.y != 0 ? 1u : 0u) << (4 * q + 1);
        w2 |= (v.z != 0 ? 1u : 0u) << (4 * q + 2);
        w2 |= (v.w != 0 ? 1u : 0u) << (4 * q + 3);
    }
    uint32_t c = (uint32_t)(__popc(w0) + __popc(w1) + __popc(w2));
    packed[r] = make_uint4(w0, w1, w2, c);
}

__global__ __launch_bounds__(256) void norm_kernel(const float* __restrict__ x,
                                                   float* __restrict__ norms) {
    const int w = (int)((blockIdx.x * 256 + threadIdx.x) >> 6);
    const int lane = threadIdx.x & 63;
    if (w >= B_ROWS) return;
    const float* row = x + (size_t)w * DIMS;
    float ss = 0.f;
#pragma unroll
    for (int u = 0; u < DIMS / 64; ++u) { float v = row[lane + 64 * u]; ss += v * v; }
#pragma unroll
    for (int m = 1; m < 64; m <<= 1) ss += __shfl_xor(ss, m, 64);
    if (lane == 0) norms[w] = fmaxf(sqrtf(ss), 1e-12f);
}

// 512 threads = 8 waves = 8 row-pairs per block; grid 256
__global__ __launch_bounds__(512, 4) void main_kernel(const float* __restrict__ x,
                                                      const uint4* __restrict__ packed,
                                                      const float* __restrict__ norms,
                                                      float* __restrict__ acc) {
    __shared__ uint4 tab[B_ROWS];   // 64 KB label bitmask+count table
    const int tid = threadIdx.x;
#pragma unroll
    for (int k = 0; k < B_ROWS / 512; ++k) tab[tid + 512 * k] = packed[tid + 512 * k];
    __syncthreads();

    const int lane = tid & 63;
    const int wid  = tid >> 6;
    const int pr   = (int)blockIdx.x * 8 + wid;      // [0, 2048)
    const int r0   = pr, r1 = pr + HALF_ROWS;
    const uint4 m0 = tab[r0], m1 = tab[r1];
    const uint32_t base = (uint32_t)pr * (uint32_t)B_ROWS;

    // ---- pass 1: gumbel-argmax positive.
    // ja > 0.5 <=> 2*it > union exactly (min rational separation 1/320 >> ulp);
    // threefry evaluated only in iterations where some lane has a candidate.
    u64 best0 = 0ull, best1 = 0ull;
    for (int jb = 0; jb < B_ROWS; jb += 64) {
        const int j = jb + lane;
        const uint4 mj = tab[j];
        const uint32_t it0 = inter3(m0, mj);
        const uint32_t u0  = m0.w + mj.w - it0;
        const uint32_t it1 = inter3(m1, mj);
        const uint32_t u1  = m1.w + mj.w - it1;
        const bool c0 = (it0 << 1) > u0;
        const bool c1 = (it1 << 1) > u1;
        if (__any(c0 || c1)) {
            uint32_t o0, o1;
            tf2x32_key42(base + (uint32_t)j, base + (uint32_t)j + HCNT, o0, o1);
            const uint32_t ixor = 0xFFFFFFFFu ^ (uint32_t)j;
            if (c0) {
                u64 key = ((u64)(o0 >> 9) << 32) | (u64)ixor;
                best0 = key > best0 ? key : best0;
            }
            if (c1) {
                u64 key = ((u64)(o1 >> 9) << 32) | (u64)ixor;
                best1 = key > best1 ? key : best1;
            }
        }
    }
#pragma unroll
    for (int m = 1; m < 64; m <<= 1) {
        u64 ob0 = shflx64(best0, m), ob1 = shflx64(best1, m);
        best0 = ob0 > best0 ? ob0 : best0;
        best1 = ob1 > best1 ? ob1 : best1;
    }
    const bool valid0 = best0 != 0ull, valid1 = best1 != 0ull;
    const int pos0 = valid0 ? (int)(0xFFFFFFFFu ^ (uint32_t)(best0 & 0xFFFFFFFFull)) : 0;
    const int pos1 = valid1 ? (int)(0xFFFFFFFFu ^ (uint32_t)(best1 & 0xFFFFFFFFull)) : 0;

    // positive's jaccard as exact integer pair (it_p, u_p)
    uint32_t itp0, up0, itp1, up1;
    {
        uint4 mp = tab[pos0];
        itp0 = inter3(m0, mp);
        up0  = m0.w + mp.w - itp0;
        mp = tab[pos1];
        itp1 = inter3(m1, mp);
        up1  = m1.w + mp.w - itp1;
    }

    // ---- pass 2: top-5 negatives by (jacc desc, index asc), -inf filler.
    // neg mask: it*u_p < it_p*u (exact); IEEE div only when candidate can
    // beat the lane's current 5th-best (conservative rcp upper bound).
    u64 t0[5] = {0,0,0,0,0}, t1[5] = {0,0,0,0,0};
    for (int jb = 0; jb < B_ROWS; jb += 64) {
        const int j = jb + lane;
        const uint4 mj = tab[j];
        const uint32_t ixor = 0xFFFFFFFFu ^ (uint32_t)j;
        const uint32_t cjw = mj.w;
        {
            const uint32_t it = inter3(m0, mj);
            const uint32_t u  = m0.w + cjw - it;
            if (__umul24(it, up0) < __umul24(itp0, u)) {
                const float fit = (float)it;
                const float ub = fit * __builtin_amdgcn_rcpf((float)u) * 1.000004f;
                const u64 t4 = t0[4];
                const bool t4real = (t4 >> 63) != 0ull;
                const float t4ja = __uint_as_float(((uint32_t)(t4 >> 32)) & 0x7FFFFFFFu);
                if (!t4real || ub >= t4ja) {
                    const float ja = fit / (float)u;   // IEEE, exact ties
                    top5_insert(t0, ((u64)(__float_as_uint(ja) | 0x80000000u) << 32) | (u64)ixor);
                }
            } else {
                top5_insert(t0, (0x007FFFFFull << 32) | (u64)ixor);  // -inf filler
            }
        }
        {
            const uint32_t it = inter3(m1, mj);
            const uint32_t u  = m1.w + cjw - it;
            if (__umul24(it, up1) < __umul24(itp1, u)) {
                const float fit = (float)it;
                const float ub = fit * __builtin_amdgcn_rcpf((float)u) * 1.000004f;
                const u64 t4 = t1[4];
                const bool t4real = (t4 >> 63) != 0ull;
                const float t4ja = __uint_as_float(((uint32_t)(t4 >> 32)) & 0x7FFFFFFFu);
                if (!t4real || ub >= t4ja) {
                    const float ja = fit / (float)u;
                    top5_insert(t1, ((u64)(__float_as_uint(ja) | 0x80000000u) << 32) | (u64)ixor);
                }
            } else {
                top5_insert(t1, (0x007FFFFFull << 32) | (u64)ixor);
            }
        }
    }
#pragma unroll
    for (int m = 1; m < 64; m <<= 1) {
        u64 o[5];
#pragma unroll
        for (int k = 0; k < 5; ++k) o[k] = shflx64(t0[k], m);
        merge_top5(t0, o);
#pragma unroll
        for (int k = 0; k < 5; ++k) o[k] = shflx64(t1[k], m);
        merge_top5(t1, o);
    }

    int tg0[6], tg1[6];
    tg0[0] = pos0; tg1[0] = pos1;
#pragma unroll
    for (int k = 0; k < 5; ++k) {
        tg0[k + 1] = (int)(0xFFFFFFFFu ^ (uint32_t)(t0[k] & 0xFFFFFFFFull));
        tg1[k + 1] = (int)(0xFFFFFFFFu ^ (uint32_t)(t1[k] & 0xFFFFFFFFull));
    }

    // ---- cosine sims at the 6 sampled indices per row (12 dots of length 512) ----
    const float* xr0 = x + (size_t)r0 * DIMS;
    const float* xr1 = x + (size_t)r1 * DIMS;
    float v0[8], v1[8];
#pragma unroll
    for (int u = 0; u < 8; ++u) { v0[u] = xr0[lane + 64 * u]; v1[u] = xr1[lane + 64 * u]; }
    float s0[6], s1[6];
#pragma unroll
    for (int q = 0; q < 6; ++q) {
        const float* p0 = x + (size_t)tg0[q] * DIMS;
        const float* p1 = x + (size_t)tg1[q] * DIMS;
        float a = 0.f, b = 0.f;
#pragma unroll
        for (int u = 0; u < 8; ++u) {
            a += v0[u] * p0[lane + 64 * u];
            b += v1[u] * p1[lane + 64 * u];
        }
#pragma unroll
        for (int m = 1; m < 64; m <<= 1) {
            a += __shfl_xor(a, m, 64);
            b += __shfl_xor(b, m, 64);
        }
        s0[q] = a; s1[q] = b;
    }

    if (lane == 0) {
        if (valid0) {
            const float nr = norms[r0];
            float sp = s0[0] / (nr * norms[tg0[0]]);
            float sen = 0.f;
#pragma unroll
            for (int k = 1; k < 6; ++k) sen += expf(s0[k] / (nr * norms[tg0[k]]));
            float ep = expf(sp);
            float loss = -logf(ep / (ep + sen));
            atomicAdd(&acc[0], loss);
            atomicAdd(&acc[1], 1.0f);
        }
        if (valid1) {
            const float nr = norms[r1];
            float sp = s1[0] / (nr * norms[tg1[0]]);
            float sen = 0.f;
#pragma unroll
            for (int k = 1; k < 6; ++k) sen += expf(s1[k] / (nr * norms[tg1[k]]));
            float ep = expf(sp);
            float loss = -logf(ep / (ep + sen));
            atomicAdd(&acc[0], loss);
            atomicAdd(&acc[1], 1.0f);
        }
    }
}

__global__ void final_kernel(const float* __restrict__ acc, float* __restrict__ out) {
    out[0] = acc[0] / acc[1];
}

extern "C" void kernel_launch(void* const* d_in, const int* in_sizes, int n_in,
                              void* d_out, int out_size, void* d_ws, size_t ws_size,
                              hipStream_t stream) {
    const float* x      = (const float*)d_in[0];
    const int*   labels = (const int*)d_in[1];
    float* out = (float*)d_out;

    char* ws = (char*)d_ws;
    float* acc    = (float*)ws;                  // 16 B (2 floats used)
    float* norms  = (float*)(ws + 16);           // 4096 * 4 B
    uint4* packed = (uint4*)(ws + 16 + 16384);   // 4096 * 16 B

    hipMemsetAsync(acc, 0, 16, stream);
    hipLaunchKernelGGL(pack_kernel, dim3(64),   dim3(64),  0, stream, labels, packed);
    hipLaunchKernelGGL(norm_kernel, dim3(1024), dim3(256), 0, stream, x, norms);
    hipLaunchKernelGGL(main_kernel, dim3(256),  dim3(512), 0, stream, x, packed, norms, acc);
    hipLaunchKernelGGL(final_kernel, dim3(1), dim3(1), 0, stream, acc, out);
}

// Round 3
// 209.422 us; speedup vs baseline: 1.1287x; 1.1287x over previous
//
#include <hip/hip_runtime.h>
#include <stdint.h>

// Problem constants (fixed by reference setup_inputs): B=4096, D=512, L=80
#define B_ROWS 4096
#define DIMS   512
#define NLAB   80
#define HALF_ROWS 2048
#define HCNT   8388608u   // B*B/2 = 2^23, threefry counter split point
#define CHUNK  1024       // j-range per wave (4 waves per row-pair)

typedef unsigned long long u64;

__device__ __forceinline__ uint32_t rotl32(uint32_t x, uint32_t d) {
    return (x << d) | (x >> (32u - d));
}

// JAX threefry2x32 with key = (0, 42)
__device__ __forceinline__ void tf2x32_key42(uint32_t c0, uint32_t c1,
                                             uint32_t& o0, uint32_t& o1) {
    const uint32_t ks0 = 0u;
    const uint32_t ks1 = 42u;
    const uint32_t ks2 = 0x1BD11BDAu ^ 0u ^ 42u;
    uint32_t x0 = c0 + ks0;
    uint32_t x1 = c1 + ks1;
#define TF_RND(r) { x0 += x1; x1 = rotl32(x1, (r)); x1 ^= x0; }
    TF_RND(13u) TF_RND(15u) TF_RND(26u) TF_RND(6u)
    x0 += ks1; x1 += ks2 + 1u;
    TF_RND(17u) TF_RND(29u) TF_RND(16u) TF_RND(24u)
    x0 += ks2; x1 += ks0 + 2u;
    TF_RND(13u) TF_RND(15u) TF_RND(26u) TF_RND(6u)
    x0 += ks0; x1 += ks1 + 3u;
    TF_RND(17u) TF_RND(29u) TF_RND(16u) TF_RND(24u)
    x0 += ks1; x1 += ks2 + 4u;
    TF_RND(13u) TF_RND(15u) TF_RND(26u) TF_RND(6u)
    x0 += ks2; x1 += ks0 + 5u;
#undef TF_RND
    o0 = x0; o1 = x1;
}

__device__ __forceinline__ u64 shflx64(u64 v, int m) {
    uint32_t lo = __shfl_xor((uint32_t)(v & 0xFFFFFFFFull), m, 64);
    uint32_t hi = __shfl_xor((uint32_t)(v >> 32), m, 64);
    return ((u64)hi << 32) | (u64)lo;
}

__device__ __forceinline__ uint32_t umx(uint32_t a, uint32_t b) { return a > b ? a : b; }
__device__ __forceinline__ uint32_t umn(uint32_t a, uint32_t b) { return a < b ? a : b; }

// unconditional sorted-desc insert: t[4]=max(t[4],k), bubble (8 min/max)
__device__ __forceinline__ void ins5_u32(uint32_t* t, uint32_t k) {
    t[4] = umx(t[4], k);
    uint32_t hi, lo;
    hi = umx(t[3], t[4]); lo = umn(t[3], t[4]); t[3] = hi; t[4] = lo;
    hi = umx(t[2], t[3]); lo = umn(t[2], t[3]); t[2] = hi; t[3] = lo;
    hi = umx(t[1], t[2]); lo = umn(t[1], t[2]); t[1] = hi; t[2] = lo;
    hi = umx(t[0], t[1]); lo = umn(t[0], t[1]); t[0] = hi; t[1] = lo;
}

// merge two sorted-desc 5-lists, keep top-5 (min/max network)
__device__ __forceinline__ void merge5_u32(uint32_t* A, const uint32_t* Bv) {
    uint32_t a0=A[0],a1=A[1],a2=A[2],a3=A[3],a4=A[4];
    uint32_t b0=Bv[0],b1=Bv[1],b2=Bv[2],b3=Bv[3],b4=Bv[4];
    uint32_t m0 = umx(a0, b0);
    uint32_t m1 = umx(umx(a1, b1), umn(a0, b0));
    uint32_t m2 = umx(umx(a2, b2), umx(umn(a0, b1), umn(a1, b0)));
    uint32_t m3 = umx(umx(a3, b3), umx(umx(umn(a0, b2), umn(a1, b1)), umn(a2, b0)));
    uint32_t m4 = umx(umx(a4, b4), umx(umx(umn(a0, b3), umn(a1, b2)),
                                       umx(umn(a2, b1), umn(a3, b0))));
    A[0]=m0; A[1]=m1; A[2]=m2; A[3]=m3; A[4]=m4;
}

// ---------------- kernels ----------------

// fused: zero acc + pack labels (ballot) + row norms. 1 wave per row.
__global__ __launch_bounds__(256) void prep_kernel(const float* __restrict__ x,
                                                   const int* __restrict__ labels,
                                                   uint2* __restrict__ pA,
                                                   uint32_t* __restrict__ pB,
                                                   float* __restrict__ norms,
                                                   float* __restrict__ acc) {
    const int tid = threadIdx.x;
    const int lane = tid & 63;
    const int row = blockIdx.x * 4 + (tid >> 6);
    if (blockIdx.x == 0 && tid == 0) { acc[0] = 0.f; acc[1] = 0.f; }
    const int* lr = labels + (size_t)row * NLAB;
    const int la = lr[lane];
    const int lb = (lane < 16) ? lr[64 + lane] : 0;
    const u64 b0 = __ballot(la != 0);
    const u64 b1 = __ballot(lb != 0);          // lanes >=16 contribute 0
    const uint32_t w2 = (uint32_t)b1 & 0xFFFFu;
    const uint32_t cnt = (uint32_t)__popcll(b0) + (uint32_t)__popc(w2);
    if (lane == 0) {
        pA[row] = make_uint2((uint32_t)b0, (uint32_t)(b0 >> 32));
        pB[row] = w2 | (cnt << 16);
    }
    const float* xr = x + (size_t)row * DIMS;
    float ss = 0.f;
#pragma unroll
    for (int u = 0; u < 8; ++u) { float v = xr[lane + 64 * u]; ss += v * v; }
#pragma unroll
    for (int m = 1; m < 64; m <<= 1) ss += __shfl_xor(ss, m, 64);
    if (lane == 0) norms[row] = fmaxf(sqrtf(ss), 1e-12f);
}

// 1024 threads = 16 waves = 4 row-pairs x 4 j-chunk subs. grid 512 -> 2 blocks/CU,
// 32 waves/CU (occupancy cap). LDS: 48KB table + ~1.2KB scratch.
__global__ __launch_bounds__(1024, 8) void main_kernel(const float* __restrict__ x,
                                                       const uint2* __restrict__ pA,
                                                       const uint32_t* __restrict__ pB,
                                                       const float* __restrict__ norms,
                                                       float* __restrict__ acc) {
    __shared__ uint2    tabA[B_ROWS];        // w0,w1           (32 KB)
    __shared__ uint32_t tabB[B_ROWS];        // w2 | cnt<<16    (16 KB)
    __shared__ u64      bestL[4][2][4];
    __shared__ uint32_t keysL[4][2][4][5];
    __shared__ uint32_t tgL[4][12];          // [pos0,n0*5,pos1,n1*5]
    __shared__ float    simsL[4][12];
    __shared__ uint32_t validL[4];

    const int tid = threadIdx.x;
#pragma unroll
    for (int k = 0; k < 4; ++k) {
        tabA[tid + 1024 * k] = pA[tid + 1024 * k];
        tabB[tid + 1024 * k] = pB[tid + 1024 * k];
    }
    __syncthreads();

    const int lane = tid & 63;
    const int wid  = tid >> 6;               // 0..15
    const int g    = wid >> 2;               // row-pair group in block
    const int sub  = wid & 3;                // j-chunk
    const int pr   = (int)blockIdx.x * 4 + g;        // [0,2048)
    const int r0 = pr, r1 = pr + HALF_ROWS;
    const uint2    a0r = tabA[r0]; const uint32_t b0r = tabB[r0];
    const uint2    a1r = tabA[r1]; const uint32_t b1r = tabB[r1];
    const uint32_t m20 = b0r & 0xFFFFu, cw0 = b0r >> 16;
    const uint32_t m21 = b1r & 0xFFFFu, cw1 = b1r >> 16;
    const uint32_t base = (uint32_t)pr * (uint32_t)B_ROWS;
    const int jbase = sub * CHUNK;

    // ---- pass 1: gumbel-argmax positive over this wave's j-chunk.
    // ja > 0.5 <=> 2*it > union exactly; threefry only when a lane has a candidate.
    u64 best0 = 0ull, best1 = 0ull;
    for (int jb = 0; jb < CHUNK; jb += 64) {
        const int j = jbase + jb + lane;
        const uint2 aj = tabA[j];
        const uint32_t bj = tabB[j];
        const uint32_t m2j = bj & 0xFFFFu, cj = bj >> 16;
        const uint32_t it0 = (uint32_t)(__popc(a0r.x & aj.x) + __popc(a0r.y & aj.y) + __popc(m20 & m2j));
        const uint32_t u0  = cw0 + cj - it0;
        const uint32_t it1 = (uint32_t)(__popc(a1r.x & aj.x) + __popc(a1r.y & aj.y) + __popc(m21 & m2j));
        const uint32_t u1  = cw1 + cj - it1;
        const bool c0 = (it0 << 1) > u0;
        const bool c1 = (it1 << 1) > u1;
        if (__any(c0 || c1)) {
            uint32_t o0, o1;
            tf2x32_key42(base + (uint32_t)j, base + (uint32_t)j + HCNT, o0, o1);
            const uint32_t ixor = 0xFFFFFFFFu ^ (uint32_t)j;
            if (c0) { u64 key = ((u64)(o0 >> 9) << 32) | (u64)ixor; if (key > best0) best0 = key; }
            if (c1) { u64 key = ((u64)(o1 >> 9) << 32) | (u64)ixor; if (key > best1) best1 = key; }
        }
    }
#pragma unroll
    for (int m = 1; m < 64; m <<= 1) {
        u64 o0 = shflx64(best0, m), o1 = shflx64(best1, m);
        if (o0 > best0) best0 = o0;
        if (o1 > best1) best1 = o1;
    }
    if (lane == 0) { bestL[g][0][sub] = best0; bestL[g][1][sub] = best1; }
    __syncthreads();
    // cross-sub combine (uniform broadcast reads)
    u64 B0 = bestL[g][0][0], B1 = bestL[g][1][0];
#pragma unroll
    for (int s = 1; s < 4; ++s) {
        u64 v0 = bestL[g][0][s]; if (v0 > B0) B0 = v0;
        u64 v1 = bestL[g][1][s]; if (v1 > B1) B1 = v1;
    }
    const bool valid0 = B0 != 0ull, valid1 = B1 != 0ull;
    const int pos0 = valid0 ? (int)(~(uint32_t)(B0 & 0xFFFFFFFFull)) : 0;
    const int pos1 = valid1 ? (int)(~(uint32_t)(B1 & 0xFFFFFFFFull)) : 0;

    // positive's jaccard as exact integer pair (it_p, u_p)
    uint32_t itp0, up0, itp1, up1;
    {
        uint2 ap = tabA[pos0]; uint32_t bp = tabB[pos0];
        itp0 = (uint32_t)(__popc(a0r.x & ap.x) + __popc(a0r.y & ap.y) + __popc(m20 & bp & 0xFFFFu));
        up0  = cw0 + (bp >> 16) - itp0;
        ap = tabA[pos1]; bp = tabB[pos1];
        itp1 = (uint32_t)(__popc(a1r.x & ap.x) + __popc(a1r.y & ap.y) + __popc(m21 & bp & 0xFFFFu));
        up1  = cw1 + (bp >> 16) - itp1;
    }

    // ---- pass 2: top-5 negatives, exact u32 keys ((floor(it*2^19/u)+1)<<12 | ~j).
    // Distinct rationals separated >= 2^-19*41 -> key strictly monotone; true ties
    // collide -> index tie-break matches lax.top_k. Seeds = -inf fillers (key19=0)
    // at this chunk's lowest indices.
    uint32_t t0[5], t1[5];
#pragma unroll
    for (int k = 0; k < 5; ++k) {
        const uint32_t fk = (uint32_t)(~(jbase + k)) & 0xFFFu;
        t0[k] = fk; t1[k] = fk;
    }
    for (int jb = 0; jb < CHUNK; jb += 64) {
        const int j = jbase + jb + lane;
        const uint2 aj = tabA[j];
        const uint32_t bj = tabB[j];
        const uint32_t m2j = bj & 0xFFFFu, cj = bj >> 16;
        const uint32_t jx = (~(uint32_t)j) & 0xFFFu;
        {
            const uint32_t it = (uint32_t)(__popc(a0r.x & aj.x) + __popc(a0r.y & aj.y) + __popc(m20 & m2j));
            const uint32_t u  = cw0 + cj - it;
            float f = (float)it * __builtin_amdgcn_rcpf((float)u) * 524288.0f;
            uint32_t ak = (uint32_t)f;                 // in {K-1,K,K+1}, K=floor exact
            if ((((ak + 2u) << 12) | 0xFFFu) > t0[4] &&
                __umul24(it, up0) < __umul24(itp0, u)) {
                const uint32_t n = it << 19;
                int r = (int)(n - ak * u);
                if (r < 0) { ak--; r += (int)u; }
                if (r >= (int)u) ak++;
                ins5_u32(t0, ((ak + 1u) << 12) | jx);
            }
        }
        {
            const uint32_t it = (uint32_t)(__popc(a1r.x & aj.x) + __popc(a1r.y & aj.y) + __popc(m21 & m2j));
            const uint32_t u  = cw1 + cj - it;
            float f = (float)it * __builtin_amdgcn_rcpf((float)u) * 524288.0f;
            uint32_t ak = (uint32_t)f;
            if ((((ak + 2u) << 12) | 0xFFFu) > t1[4] &&
                __umul24(it, up1) < __umul24(itp1, u)) {
                const uint32_t n = it << 19;
                int r = (int)(n - ak * u);
                if (r < 0) { ak--; r += (int)u; }
                if (r >= (int)u) ak++;
                ins5_u32(t1, ((ak + 1u) << 12) | jx);
            }
        }
    }
#pragma unroll
    for (int m = 1; m < 64; m <<= 1) {
        uint32_t o[5];
#pragma unroll
        for (int k = 0; k < 5; ++k) o[k] = __shfl_xor(t0[k], m, 64);
        merge5_u32(t0, o);
#pragma unroll
        for (int k = 0; k < 5; ++k) o[k] = __shfl_xor(t1[k], m, 64);
        merge5_u32(t1, o);
    }
    if (lane == 0) {
#pragma unroll
        for (int k = 0; k < 5; ++k) {
            keysL[g][0][sub][k] = t0[k];
            keysL[g][1][sub][k] = t1[k];
        }
    }
    __syncthreads();
    if (sub == 0) {
        uint32_t f0[5], f1[5];
#pragma unroll
        for (int k = 0; k < 5; ++k) { f0[k] = keysL[g][0][0][k]; f1[k] = keysL[g][1][0][k]; }
#pragma unroll
        for (int s = 1; s < 4; ++s) {
            uint32_t o[5];
#pragma unroll
            for (int k = 0; k < 5; ++k) o[k] = keysL[g][0][s][k];
            merge5_u32(f0, o);
#pragma unroll
            for (int k = 0; k < 5; ++k) o[k] = keysL[g][1][s][k];
            merge5_u32(f1, o);
        }
        if (lane == 0) {
            tgL[g][0] = (uint32_t)pos0;
            tgL[g][6] = (uint32_t)pos1;
#pragma unroll
            for (int k = 0; k < 5; ++k) {
                tgL[g][1 + k] = (~f0[k]) & 0xFFFu;
                tgL[g][7 + k] = (~f1[k]) & 0xFFFu;
            }
            validL[g] = (valid0 ? 1u : 0u) | (valid1 ? 2u : 0u);
        }
    }
    __syncthreads();

    // ---- cosine numerator dots: 12 per group, 3 per wave ----
#pragma unroll
    for (int k = 0; k < 3; ++k) {
        const int d = sub + 4 * k;
        const int row = (d >= 6) ? r1 : r0;
        const int tgt = (int)tgL[g][d];
        const float* pa = x + (size_t)row * DIMS;
        const float* pb = x + (size_t)tgt * DIMS;
        float s = 0.f;
#pragma unroll
        for (int u = 0; u < 8; ++u) s += pa[lane + 64 * u] * pb[lane + 64 * u];
#pragma unroll
        for (int m = 1; m < 64; m <<= 1) s += __shfl_xor(s, m, 64);
        if (lane == 0) simsL[g][d] = s;
    }
    __syncthreads();

    // ---- loss: sub 0 handles row0, sub 1 handles row1 of its group ----
    if (sub < 2 && lane == 0) {
        if ((validL[g] >> sub) & 1u) {
            const int row = sub ? r1 : r0;
            const int off = sub * 6;
            const float nr = norms[row];
            const float sp = simsL[g][off] / (nr * norms[tgL[g][off]]);
            float sen = 0.f;
#pragma unroll
            for (int q = 1; q < 6; ++q)
                sen += expf(simsL[g][off + q] / (nr * norms[tgL[g][off + q]]));
            const float ep = expf(sp);
            atomicAdd(&acc[0], -logf(ep / (ep + sen)));
            atomicAdd(&acc[1], 1.0f);
        }
    }
}

__global__ void final_kernel(const float* __restrict__ acc, float* __restrict__ out) {
    out[0] = acc[0] / acc[1];
}

extern "C" void kernel_launch(void* const* d_in, const int* in_sizes, int n_in,
                              void* d_out, int out_size, void* d_ws, size_t ws_size,
                              hipStream_t stream) {
    const float* x      = (const float*)d_in[0];
    const int*   labels = (const int*)d_in[1];
    float* out = (float*)d_out;

    char* ws = (char*)d_ws;
    float*    acc   = (float*)ws;                       // 16 B
    float*    norms = (float*)(ws + 16);                // 4096 * 4 B
    uint2*    pA    = (uint2*)(ws + 16 + 16384);        // 4096 * 8 B
    uint32_t* pB    = (uint32_t*)(ws + 16 + 16384 + 32768); // 4096 * 4 B

    hipLaunchKernelGGL(prep_kernel,  dim3(1024), dim3(256),  0, stream, x, labels, pA, pB, norms, acc);
    hipLaunchKernelGGL(main_kernel,  dim3(512),  dim3(1024), 0, stream, x, pA, pB, norms, acc);
    hipLaunchKernelGGL(final_kernel, dim3(1),    dim3(1),    0, stream, acc, out);
}